// Round 18
// baseline (5288.930 us; speedup 1.0000x reference)
//
#include <hip/hip_runtime.h>
#include <math.h>

#define BB 512
#define SS 2048
#define DD 19
#define HH 40
#define G4 160
#define CH 32
#define NCH (SS / CH)   // 64 chunks
#define RS 41
#define HS 48
#define GT 320          // gate threads: 5 waves, tid = 8u + 4*half + g

// quad_perm DPP (VALU pipe): xor1=0xB1, xor2=0x4E, rev=0x1B (validated R8/R14)
#define QPERM(v, ctrl) __int_as_float(__builtin_amdgcn_mov_dpp(__float_as_int(v), (ctrl), 0xf, 0xf, true))
// row_half_mirror within 8-lane group (validated R15)
#define HMIR(v) __int_as_float(__builtin_amdgcn_mov_dpp(__float_as_int(v), 0x141, 0xf, 0xf, true))

__device__ __forceinline__ float gate_act(float a, float mulk) {
    float e = __expf(a * mulk);
    float r = __builtin_amdgcn_rcpf(e + 1.0f);
    return fmaf(-mulk, r, 1.0f);
}
__device__ __forceinline__ float tanh_fast(float x) {
    float e = __expf(2.0f * x);
    float r = __builtin_amdgcn_rcpf(e + 1.0f);
    return fmaf(-2.0f, r, 1.0f);
}
__device__ __forceinline__ float sigm_fast(float x) {
    float e = __expf(x);
    float r = __builtin_amdgcn_rcpf(e + 1.0f);
    return fmaf(-1.0f, r, 1.0f);
}

// ===== Kernel 1: recurrence; per-chunk xpart precompute in registers =====
__global__ __launch_bounds__(GT, 1)
void lstm_seq(const float* __restrict__ x,
              const float* __restrict__ W_ih,
              const float* __restrict__ W_hh,
              const float* __restrict__ b_ih,
              const float* __restrict__ b_hh,
              const float* __restrict__ log_thr,
              float* __restrict__ hist,
              float* __restrict__ out) {
    __shared__ __align__(16) float s_ring[CH + 1][HS];   // row t = h input of step t
    __shared__ __align__(16) float s_x[CH][20];          // staged x chunk, [19]=pad 0

    const int tid = threadIdx.x;
    const int b = blockIdx.x;
    if (tid < HH) s_ring[0][tid] = 0.0f;
    if (tid < CH) s_x[tid][19] = 0.0f;   // pad, never re-written

    // tid = 8u + 4*half + g
    const int u = tid >> 3;
    const int half = (tid >> 2) & 1;
    const int g = tid & 3;
    const int grow = g * HH + u;
    const float mulk = (g == 2) ? 2.0f : 1.0f;

    // ---- weights: half a row per thread (VGPR-resident, proven R13-R15) ----
    float whh[20];
    {
        const float4* wr = (const float4*)&W_hh[grow * HH + half * 20];
#pragma unroll
        for (int q = 0; q < 5; ++q) {
            float4 f = wr[q];
            whh[4*q] = f.x; whh[4*q+1] = f.y; whh[4*q+2] = f.z; whh[4*q+3] = f.w;
        }
    }
    float wih[10];
#pragma unroll
    for (int d = 0; d < 10; ++d) {
        int idx = half * 10 + d;
        wih[d] = (idx < DD) ? W_ih[grow * DD + idx] : 0.0f;   // wih[9]=0 for half 1
    }
    const float bsumv = half ? 0.0f : (b_ih[grow] + b_hh[grow]);

    float cc = 0.0f, hh = 0.0f;      // live in (tid&7)==0 lanes

    // x prefetch: 608 floats / 320 threads -> 2 regs
    const int i0 = tid, i1 = tid + GT;
    const int st0 = i0 / DD, d0 = i0 % DD;
    const int st1 = i1 / DD, d1 = i1 % DD;
    const bool has1 = (i1 < CH * DD);
    float xr0, xr1 = 0.f;
    {
        const float* xp = x + (size_t)b * SS * DD;
        xr0 = xp[i0];
        if (has1) xr1 = xp[i1];
    }

    float* hb = hist + (size_t)b * SS * HH;
    __syncthreads();

    for (int ch = 0; ch < NCH; ++ch) {
        // ---- chunk prologue: hist copy (prev chunk), h carry, x stage ----
        if (ch > 0) {
            const size_t cb = (size_t)(ch - 1) * CH * HH;
#pragma unroll
            for (int it = 0; it < 4; ++it) {
                int i = tid + it * GT;                 // CH*HH = 1280 = 4*GT
                hb[cb + i] = s_ring[1 + i / HH][i % HH];
            }
            if (tid < HH) s_ring[0][tid] = s_ring[CH][tid];   // carry h
        }
        s_x[st0][d0] = xr0;
        if (has1) s_x[st1][d1] = xr1;
        if (ch + 1 < NCH) {
            const float* xp = x + ((size_t)b * SS + (size_t)(ch + 1) * CH) * DD;
            xr0 = xp[i0];
            if (has1) xr1 = xp[i1];
        }
        __syncthreads();   // drains hist stores (amortized) + orders ring/s_x

        // ---- xpart precompute: all 32 steps into registers (static-indexed) ----
        float xp[CH];
#pragma unroll
        for (int t = 0; t < CH; ++t) {
            const float4* xr4 = (const float4*)&s_x[t][0];
            float4 A = xr4[0], B = xr4[1], C = xr4[2], D = xr4[3], E = xr4[4];
            float p0 = bsumv, p1 = 0.f;
            if (half == 0) {
                p0 = fmaf(A.x, wih[0], p0); p1 = fmaf(A.y, wih[1], p1);
                p0 = fmaf(A.z, wih[2], p0); p1 = fmaf(A.w, wih[3], p1);
                p0 = fmaf(B.x, wih[4], p0); p1 = fmaf(B.y, wih[5], p1);
                p0 = fmaf(B.z, wih[6], p0); p1 = fmaf(B.w, wih[7], p1);
                p0 = fmaf(C.x, wih[8], p0); p1 = fmaf(C.y, wih[9], p1);
            } else {
                p0 = fmaf(C.z, wih[0], p0); p1 = fmaf(C.w, wih[1], p1);
                p0 = fmaf(D.x, wih[2], p0); p1 = fmaf(D.y, wih[3], p1);
                p0 = fmaf(D.z, wih[4], p0); p1 = fmaf(D.w, wih[5], p1);
                p0 = fmaf(E.x, wih[6], p0); p1 = fmaf(E.y, wih[7], p1);
                p0 = fmaf(E.z, wih[8], p0); p1 = fmaf(E.w, wih[9], p1);  // E.w=pad=0
            }
            xp[t] = p0 + p1;
        }

        // ---- 32 steps: ONLY 5 b128 h-reads + 1 write on the DS pipe ----
#pragma unroll
        for (int t = 0; t < CH; ++t) {
            const float4* h4 = (const float4*)&s_ring[t][half * 20];
            float a0 = xp[t], a1 = 0.f;
#pragma unroll
            for (int q = 0; q < 5; ++q) {
                float4 f = h4[q];
                a0 = fmaf(f.x, whh[4*q+0], a0);
                a1 = fmaf(f.y, whh[4*q+1], a1);
                a0 = fmaf(f.z, whh[4*q+2], a0);
                a1 = fmaf(f.w, whh[4*q+3], a1);
            }
            float acc = a0 + a1;
            float other = QPERM(HMIR(acc), 0x1B);   // half-swap, VALU-only
            float full = acc + other;
            float av = gate_act(full, mulk);
            float bv = QPERM(av, 0xB1);   // gate g^1
            float cv = QPERM(av, 0x4E);   // gate g^2
            float dv = QPERM(av, 0x1B);   // gate g^3
            // lane 8u+0: av=i, bv=f, cv=g~, dv=o
            if ((tid & 7) == 0) {
                cc = fmaf(bv, cc, av * cv);
                hh = dv * tanh_fast(cc);
                s_ring[t + 1][u] = hh;    // single write: next-h + history in one
            }
            __syncthreads();
        }
    }

    // final chunk history
    {
        const size_t cb = (size_t)(NCH - 1) * CH * HH;
#pragma unroll
        for (int it = 0; it < 4; ++it) {
            int i = tid + it * GT;
            hb[cb + i] = s_ring[1 + i / HH][i % HH];
        }
    }
    if ((tid & 7) == 0) {
        out[(size_t)BB * SS + (size_t)b * HH + u] = hh;
        out[(size_t)BB * SS + (size_t)BB * HH + (size_t)b * HH + u] = cc;
    }
    if (b == 0 && tid == 0) {
        out[(size_t)BB * SS + 2 * (size_t)BB * HH] = expf(log_thr[0]);
    }
}

// ================= Kernel 2: LN + MLP + head, massively parallel =================
__global__ __launch_bounds__(256, 2)
void post_mlp(const float* __restrict__ hist,
              const float* __restrict__ ln_g,
              const float* __restrict__ ln_b,
              const float* __restrict__ W1,
              const float* __restrict__ b1,
              const float* __restrict__ W2,
              const float* __restrict__ b2,
              const float* __restrict__ Wo,
              const float* __restrict__ bo,
              const float* __restrict__ log_thr,
              float* __restrict__ out) {
    __shared__ float s_rows[256][HH + 1];
    __shared__ __align__(16) float s_W1[HH * HH];
    __shared__ __align__(16) float s_W2[HH * HH];
    __shared__ float s_lng[HH], s_lnb[HH], s_Wo[HH], s_b1[HH], s_b2[HH];

    const int tid = threadIdx.x;
    const size_t base = (size_t)blockIdx.x * 256 * HH;

    for (int i = tid; i < HH * HH; i += 256) { s_W1[i] = W1[i]; s_W2[i] = W2[i]; }
    if (tid < HH) {
        s_lng[tid] = ln_g[tid]; s_lnb[tid] = ln_b[tid]; s_Wo[tid] = Wo[tid];
        s_b1[tid] = b1[tid]; s_b2[tid] = b2[tid];
    }
    for (int i = tid; i < 256 * HH; i += 256)
        s_rows[i / HH][i % HH] = hist[base + i];
    __syncthreads();

    const float bo0 = bo[0];
    const float thrv = expf(log_thr[0]);

    float hv[HH];
#pragma unroll
    for (int k = 0; k < HH; ++k) hv[k] = s_rows[tid][k];
    float m0 = 0.f, m1 = 0.f, q0 = 0.f, q1 = 0.f;
#pragma unroll
    for (int k = 0; k < HH; k += 2) {
        m0 += hv[k]; m1 += hv[k + 1];
        q0 = fmaf(hv[k], hv[k], q0); q1 = fmaf(hv[k + 1], hv[k + 1], q1);
    }
    float mu = (m0 + m1) * (1.0f / HH);
    float var = (q0 + q1) * (1.0f / HH) - mu * mu;
    float inv = 1.0f / sqrtf(var + 1e-5f);
#pragma unroll
    for (int k = 0; k < HH; ++k)
        hv[k] = fmaf((hv[k] - mu) * inv, s_lng[k], s_lnb[k]);

    float part = 0.f;
#pragma unroll
    for (int k = 0; k < HH; ++k)
        part = fmaf(sigm_fast(hv[k]), s_Wo[k], part);

#pragma unroll 2
    for (int j = 0; j < HH; ++j) {
        const float4* wr = (const float4*)&s_W1[j * HH];
        float a0 = s_b1[j], a1 = 0.f;
#pragma unroll
        for (int q = 0; q < 10; ++q) {
            float4 w4 = wr[q];
            a0 = fmaf(w4.x, hv[4*q+0], a0); a1 = fmaf(w4.y, hv[4*q+1], a1);
            a0 = fmaf(w4.z, hv[4*q+2], a0); a1 = fmaf(w4.w, hv[4*q+3], a1);
        }
        s_rows[tid][j] = tanh_fast(a0 + a1);
    }
    float rr[HH];
#pragma unroll
    for (int k = 0; k < HH; ++k) rr[k] = s_rows[tid][k];
#pragma unroll 2
    for (int j = 0; j < HH; ++j) {
        const float4* wr = (const float4*)&s_W2[j * HH];
        float a0 = s_b2[j], a1 = 0.f;
#pragma unroll
        for (int q = 0; q < 10; ++q) {
            float4 w4 = wr[q];
            a0 = fmaf(w4.x, rr[4*q+0], a0); a1 = fmaf(w4.y, rr[4*q+1], a1);
            a0 = fmaf(w4.z, rr[4*q+2], a0); a1 = fmaf(w4.w, rr[4*q+3], a1);
        }
        float r2 = tanh_fast(a0 + a1);
        part = fmaf(r2, s_Wo[j], part);
    }
    float raw = tanh_fast(part + bo0);
    float sg = (fabsf(raw) >= thrv) ? raw : 0.0f;
    out[(size_t)blockIdx.x * 256 + tid] = sg;
}

// ================= Fallback: single fused kernel (ws too small) =================
__global__ __launch_bounds__(256, 2)
void lstm_fused(const float* __restrict__ x, const float* __restrict__ W_ih,
                const float* __restrict__ W_hh, const float* __restrict__ b_ih,
                const float* __restrict__ b_hh, const float* __restrict__ ln_g,
                const float* __restrict__ ln_b, const float* __restrict__ W1,
                const float* __restrict__ b1, const float* __restrict__ W2,
                const float* __restrict__ b2, const float* __restrict__ Wo,
                const float* __restrict__ bo, const float* __restrict__ log_thr,
                float* __restrict__ out) {
    __shared__ float s_ring[CH][RS];
    __shared__ __align__(16) float s_h[2][HS];
    __shared__ __align__(16) float s_x[CH][20];
    __shared__ __align__(16) float s_W1[HH * HH];
    __shared__ __align__(16) float s_W2[HH * HH];
    __shared__ float s_lng[HH], s_lnb[HH], s_Wo[HH], s_b1[HH], s_b2[HH];
    __shared__ float s_part[256];

    const int tid = threadIdx.x;
    const int b = blockIdx.x;
    for (int i = tid; i < HH * HH; i += 256) { s_W1[i] = W1[i]; s_W2[i] = W2[i]; }
    if (tid < HH) {
        s_lng[tid] = ln_g[tid]; s_lnb[tid] = ln_b[tid]; s_Wo[tid] = Wo[tid];
        s_b1[tid] = b1[tid]; s_b2[tid] = b2[tid];
    }
    if (tid < HS) { s_h[0][tid] = 0.0f; s_h[1][tid] = 0.0f; }
    const float bo0 = bo[0];
    const float thrv = expf(log_thr[0]);
    const bool isGate = tid < 4 * HH;
    const int g = tid & 3, u = tid >> 2;
    const int grow = g * HH + u;
    const float mulk = (g == 2) ? 2.0f : 1.0f;
    float wih[DD], whh[HH], bsum = 0.0f;
    if (isGate) {
#pragma unroll
        for (int d = 0; d < DD; ++d) wih[d] = W_ih[grow * DD + d];
        const float4* wr = (const float4*)&W_hh[grow * HH];
#pragma unroll
        for (int q = 0; q < 10; ++q) {
            float4 f = wr[q];
            whh[4*q] = f.x; whh[4*q+1] = f.y; whh[4*q+2] = f.z; whh[4*q+3] = f.w;
        }
        bsum = b_ih[grow] + b_hh[grow];
    }
    float cc = 0.0f, hh = 0.0f;
    const int i0 = tid, i1 = tid + 256, i2 = tid + 512;
    const int st0 = i0 / DD, d0 = i0 % DD;
    const int st1 = i1 / DD, d1 = i1 % DD;
    const int st2 = i2 / DD, d2 = i2 % DD;
    float xr0 = 0.f, xr1 = 0.f, xr2 = 0.f;
    {
        const float* xp = x + (size_t)b * SS * DD;
        xr0 = xp[i0]; xr1 = xp[i1];
        if (i2 < CH * DD) xr2 = xp[i2];
    }
    __syncthreads();
    for (int ch = 0; ch < NCH; ++ch) {
        s_x[st0][d0] = xr0; s_x[st1][d1] = xr1;
        if (i2 < CH * DD) s_x[st2][d2] = xr2;
        if (ch + 1 < NCH) {
            const float* xp = x + ((size_t)b * SS + (size_t)(ch + 1) * CH) * DD;
            xr0 = xp[i0]; xr1 = xp[i1];
            if (i2 < CH * DD) xr2 = xp[i2];
        }
        __syncthreads();
        for (int t = 0; t < CH; ++t) {
            if (isGate) {
                const float4* h4 = (const float4*)s_h[t & 1];
                const float4* x4 = (const float4*)&s_x[t][0];
                float a0 = bsum, a1 = 0.f, a2 = 0.f, a3 = 0.f;
                float4 xa = x4[0], xb = x4[1], xc = x4[2], xd = x4[3], xe = x4[4];
                a0 = fmaf(xa.x, wih[0], a0);  a1 = fmaf(xa.y, wih[1], a1);
                a2 = fmaf(xa.z, wih[2], a2);  a3 = fmaf(xa.w, wih[3], a3);
                a0 = fmaf(xb.x, wih[4], a0);  a1 = fmaf(xb.y, wih[5], a1);
                a2 = fmaf(xb.z, wih[6], a2);  a3 = fmaf(xb.w, wih[7], a3);
                a0 = fmaf(xc.x, wih[8], a0);  a1 = fmaf(xc.y, wih[9], a1);
                a2 = fmaf(xc.z, wih[10], a2); a3 = fmaf(xc.w, wih[11], a3);
                a0 = fmaf(xd.x, wih[12], a0); a1 = fmaf(xd.y, wih[13], a1);
                a2 = fmaf(xd.z, wih[14], a2); a3 = fmaf(xd.w, wih[15], a3);
                a0 = fmaf(xe.x, wih[16], a0); a1 = fmaf(xe.y, wih[17], a1);
                a2 = fmaf(xe.z, wih[18], a2);
#pragma unroll
                for (int q = 0; q < 10; ++q) {
                    float4 f = h4[q];
                    a0 = fmaf(f.x, whh[4*q+0], a0);
                    a1 = fmaf(f.y, whh[4*q+1], a1);
                    a2 = fmaf(f.z, whh[4*q+2], a2);
                    a3 = fmaf(f.w, whh[4*q+3], a3);
                }
                float acc = (a0 + a1) + (a2 + a3);
                float av = gate_act(acc, mulk);
                float bv = __shfl_xor(av, 1);
                float cv = __shfl_xor(av, 2);
                float dv = __shfl_xor(bv, 2);
                if (g == 0) {
                    cc = fmaf(bv, cc, av * cv);
                    hh = dv * tanh_fast(cc);
                    s_h[(t + 1) & 1][u] = hh;
                    s_ring[t][u] = hh;
                }
            }
            __syncthreads();
        }
        {
            const int st = tid & 31;
            const int q8 = tid >> 5;
            float hv[HH];
#pragma unroll
            for (int k = 0; k < HH; ++k) hv[k] = s_ring[st][k];
            float m0 = 0.f, m1 = 0.f, q0 = 0.f, q1 = 0.f;
#pragma unroll
            for (int k = 0; k < HH; k += 2) {
                m0 += hv[k]; m1 += hv[k + 1];
                q0 = fmaf(hv[k], hv[k], q0); q1 = fmaf(hv[k + 1], hv[k + 1], q1);
            }
            float mu = (m0 + m1) * (1.0f / HH);
            float var = (q0 + q1) * (1.0f / HH) - mu * mu;
            float inv = 1.0f / sqrtf(var + 1e-5f);
#pragma unroll
            for (int k = 0; k < HH; ++k)
                hv[k] = fmaf((hv[k] - mu) * inv, s_lng[k], s_lnb[k]);
            float part = 0.f;
#pragma unroll
            for (int k = 0; k < HH; ++k)
                part = fmaf(sigm_fast(hv[k]), s_Wo[k], part);
            if (q8 != 0) part = 0.f;
            __syncthreads();
            float r1v[5];
#pragma unroll
            for (int jj = 0; jj < 5; ++jj) {
                int j = q8 * 5 + jj;
                const float4* wr = (const float4*)&s_W1[j * HH];
                float a0 = s_b1[j], a1 = 0.f;
#pragma unroll
                for (int q = 0; q < 10; ++q) {
                    float4 w4 = wr[q];
                    a0 = fmaf(w4.x, hv[4*q+0], a0); a1 = fmaf(w4.y, hv[4*q+1], a1);
                    a0 = fmaf(w4.z, hv[4*q+2], a0); a1 = fmaf(w4.w, hv[4*q+3], a1);
                }
                r1v[jj] = tanh_fast(a0 + a1);
                s_ring[st][j] = r1v[jj];
            }
            __syncthreads();
            float rr[HH];
#pragma unroll
            for (int k = 0; k < HH; ++k) rr[k] = s_ring[st][k];
#pragma unroll
            for (int jj = 0; jj < 5; ++jj) {
                int j = q8 * 5 + jj;
                const float4* wr = (const float4*)&s_W2[j * HH];
                float a0 = s_b2[j], a1 = 0.f;
#pragma unroll
                for (int q = 0; q < 10; ++q) {
                    float4 w4 = wr[q];
                    a0 = fmaf(w4.x, rr[4*q+0], a0); a1 = fmaf(w4.y, rr[4*q+1], a1);
                    a0 = fmaf(w4.z, rr[4*q+2], a0); a1 = fmaf(w4.w, rr[4*q+3], a1);
                }
                float r2 = tanh_fast(a0 + a1);
                part = fmaf(r2, s_Wo[j], part);
            }
            s_part[tid] = part;
            __syncthreads();
            if (tid < CH) {
                float tot = bo0;
#pragma unroll
                for (int qq = 0; qq < 8; ++qq) tot += s_part[tid + 32 * qq];
                float raw = tanh_fast(tot);
                float sg = (fabsf(raw) >= thrv) ? raw : 0.0f;
                out[(size_t)b * SS + (size_t)ch * CH + tid] = sg;
            }
        }
    }
    if (isGate && g == 0) {
        out[(size_t)BB * SS + (size_t)b * HH + u] = hh;
        out[(size_t)BB * SS + (size_t)BB * HH + (size_t)b * HH + u] = cc;
    }
    if (b == 0 && tid == 0) {
        out[(size_t)BB * SS + 2 * (size_t)BB * HH] = thrv;
    }
}

extern "C" void kernel_launch(void* const* d_in, const int* in_sizes, int n_in,
                              void* d_out, int out_size, void* d_ws, size_t ws_size,
                              hipStream_t stream) {
    const float* x    = (const float*)d_in[0];
    const float* W_ih = (const float*)d_in[1];
    const float* W_hh = (const float*)d_in[2];
    const float* b_ih = (const float*)d_in[3];
    const float* b_hh = (const float*)d_in[4];
    const float* ln_g = (const float*)d_in[5];
    const float* ln_b = (const float*)d_in[6];
    const float* W1   = (const float*)d_in[7];
    const float* b1   = (const float*)d_in[8];
    const float* W2   = (const float*)d_in[9];
    const float* b2   = (const float*)d_in[10];
    const float* Wo   = (const float*)d_in[11];
    const float* bo   = (const float*)d_in[12];
    const float* lt   = (const float*)d_in[13];
    float* out = (float*)d_out;

    const size_t need_hist = (size_t)BB * SS * HH * sizeof(float);   // 168 MB
    if (ws_size >= need_hist) {
        float* hist = (float*)d_ws;
        lstm_seq<<<dim3(BB), dim3(GT), 0, stream>>>(
            x, W_ih, W_hh, b_ih, b_hh, lt, hist, out);
        post_mlp<<<dim3(BB * SS / 256), dim3(256), 0, stream>>>(
            hist, ln_g, ln_b, W1, b1, W2, b2, Wo, bo, lt, out);
    } else {
        lstm_fused<<<dim3(BB), dim3(256), 0, stream>>>(
            x, W_ih, W_hh, b_ih, b_hh, ln_g, ln_b, W1, b1, W2, b2, Wo, bo, lt, out);
    }
}

// Round 19
// 889.130 us; speedup vs baseline: 5.9484x; 5.9484x over previous
//
#include <hip/hip_runtime.h>
#include <math.h>

#define BB 512
#define SS 2048
#define DD 19
#define HH 40
#define CH 32
#define NCH (SS / CH)   // 64 chunks
#define RS 41
#define HS 48
#define GT 320          // gate threads: 5 waves, tid = 8u + 4*half + g

// quad_perm DPP (VALU pipe): xor1=0xB1, xor2=0x4E, rev=0x1B (validated R8/R14)
#define QPERM(v, ctrl) __int_as_float(__builtin_amdgcn_mov_dpp(__float_as_int(v), (ctrl), 0xf, 0xf, true))
// row_half_mirror: lane j -> 7-(j&7) within 8-lane group (validated R15)
#define HMIR(v) __int_as_float(__builtin_amdgcn_mov_dpp(__float_as_int(v), 0x141, 0xf, 0xf, true))

__device__ __forceinline__ float gate_act(float a, float mulk) {
    float e = __expf(a * mulk);
    float r = __builtin_amdgcn_rcpf(e + 1.0f);
    return fmaf(-mulk, r, 1.0f);
}
__device__ __forceinline__ float tanh_fast(float x) {
    float e = __expf(2.0f * x);
    float r = __builtin_amdgcn_rcpf(e + 1.0f);
    return fmaf(-2.0f, r, 1.0f);
}
__device__ __forceinline__ float sigm_fast(float x) {
    float e = __expf(x);
    float r = __builtin_amdgcn_rcpf(e + 1.0f);
    return fmaf(-1.0f, r, 1.0f);
}

// ========== Kernel 1: recurrence; LDS-batched hist; all-DPP gate exchange ==========
// (R15 structure, best measured: 817 us. Half-row/thread keeps register demand ~45
//  -> allocator keeps weights VGPR-resident (R13 lesson); per-step critical region:
//  5 b128 h-reads + 20 FMA + VALU-only DPP combine + act + 1 LDS write + barrier.)
__global__ __launch_bounds__(GT, 1)
void lstm_seq(const float* __restrict__ x,
              const float* __restrict__ W_ih,
              const float* __restrict__ W_hh,
              const float* __restrict__ b_ih,
              const float* __restrict__ b_hh,
              const float* __restrict__ log_thr,
              float* __restrict__ hist,
              float* __restrict__ out) {
    __shared__ __align__(16) float s_h[2][HS];
    __shared__ __align__(16) float s_x[CH][20];
    __shared__ float s_hist[CH][HS];           // per-chunk h history (LDS, 6 KB)

    const int tid = threadIdx.x;
    const int b = blockIdx.x;
    if (tid < HS) { s_h[0][tid] = 0.0f; s_h[1][tid] = 0.0f; }
    if (tid < CH) s_x[tid][19] = 0.0f;   // pad word: never staged, must be 0

    // tid = 8u + 4*half + g : quad holds the 4 gates of one (unit, half)
    const int u = tid >> 3;          // unit 0..39
    const int half = (tid >> 2) & 1; // half of the 40-dim h dot
    const int g = tid & 3;           // gate 0..3
    const int grow = g * HH + u;
    const float mulk = (g == 2) ? 2.0f : 1.0f;

    // ---- weights: HALF a row per thread -> low pressure, VGPR-resident ----
    float whh[20];
    {
        const float4* wr = (const float4*)&W_hh[grow * HH + half * 20];
#pragma unroll
        for (int q = 0; q < 5; ++q) {
            float4 f = wr[q];
            whh[4*q] = f.x; whh[4*q+1] = f.y; whh[4*q+2] = f.z; whh[4*q+3] = f.w;
        }
    }
    float wih[10];
#pragma unroll
    for (int d = 0; d < 10; ++d) {
        int idx = half * 10 + d;
        wih[d] = (idx < DD) ? W_ih[grow * DD + idx] : 0.0f;   // wih[9]=0 for half 1
    }
    const float bsumv = half ? 0.0f : (b_ih[grow] + b_hh[grow]);

    float cc = 0.0f, hh = 0.0f;      // live in (tid&7)==0 lanes

    // x prefetch: 608 floats / 320 threads -> 2 regs
    const int i0 = tid, i1 = tid + GT;
    const int st0 = i0 / DD, d0 = i0 % DD;
    const int st1 = i1 / DD, d1 = i1 % DD;
    const bool has1 = (i1 < CH * DD);
    float xr0, xr1 = 0.f;
    {
        const float* xp = x + (size_t)b * SS * DD;
        xr0 = xp[i0];
        if (has1) xr1 = xp[i1];
    }

    float* hb = hist + (size_t)b * SS * HH;
    __syncthreads();

    for (int ch = 0; ch < NCH; ++ch) {
        s_x[st0][d0] = xr0;
        if (has1) s_x[st1][d1] = xr1;
        if (ch + 1 < NCH) {
            const float* xp = x + ((size_t)b * SS + (size_t)(ch + 1) * CH) * DD;
            xr0 = xp[i0];
            if (has1) xr1 = xp[i1];
        }
        __syncthreads();   // drains: prefetch loads + prev chunk's hist-copy stores

        // xpart for t=0 (own half of the x dot; bias folded into half 0)
        float xpart;
        {
            const float* xs = &s_x[0][half * 10];
            float p0 = bsumv, p1 = 0.f;
#pragma unroll
            for (int d = 0; d < 10; d += 2) {
                p0 = fmaf(wih[d], xs[d], p0);
                p1 = fmaf(wih[d + 1], xs[d + 1], p1);
            }
            xpart = p0 + p1;
        }

        for (int t = 0; t < CH; ++t) {
            // hoist t+1 x reads BEFORE h reads: latency overlaps the h-dot,
            // and the pre-barrier lgkm drain no longer includes them
            float xv[10];
            if (t + 1 < CH) {
                const float* xs = &s_x[t + 1][half * 10];
#pragma unroll
                for (int d = 0; d < 10; ++d) xv[d] = xs[d];
            }
            // ---- critical region: 5 x b128 h-reads + 20 FMAs ----
            const float4* h4 = (const float4*)&s_h[t & 1][half * 20];
            float a0 = xpart, a1 = 0.f;
#pragma unroll
            for (int q = 0; q < 5; ++q) {
                float4 f = h4[q];
                a0 = fmaf(f.x, whh[4*q+0], a0);
                a1 = fmaf(f.y, whh[4*q+1], a1);
                a0 = fmaf(f.z, whh[4*q+2], a0);
                a1 = fmaf(f.w, whh[4*q+3], a1);
            }
            float acc = a0 + a1;
            // half-combine entirely on VALU: half_mirror then quad-reverse
            float other = QPERM(HMIR(acc), 0x1B);
            float full = acc + other;
            float av = gate_act(full, mulk);
            // gate exchange: quad-internal DPP, all direct from av
            float bv = QPERM(av, 0xB1);   // gate g^1
            float cv = QPERM(av, 0x4E);   // gate g^2
            float dv = QPERM(av, 0x1B);   // gate g^3
            // lane 8u+0: av=i, bv=f, cv=g~, dv=o
            if ((tid & 7) == 0) {
                cc = fmaf(bv, cc, av * cv);
                hh = dv * tanh_fast(cc);
                s_h[(t + 1) & 1][u] = hh;
                s_hist[t][u] = hh;        // LDS, not global: no vmcnt at barrier
            }
            if (t + 1 < CH) {   // xpart for t+1 from already-loaded regs
                float p0 = bsumv, p1 = 0.f;
#pragma unroll
                for (int d = 0; d < 10; d += 2) {
                    p0 = fmaf(wih[d], xv[d], p0);
                    p1 = fmaf(wih[d + 1], xv[d + 1], p1);
                }
                xpart = p0 + p1;
            }
            __syncthreads();
        }

        // ---- chunk-end: cooperative coalesced copy s_hist -> global hist ----
        {
            const size_t cb = (size_t)ch * CH * HH;
#pragma unroll
            for (int it = 0; it < 4; ++it) {
                int i = tid + it * GT;                // CH*HH = 1280 = 4*GT
                hb[cb + i] = s_hist[i / HH][i % HH];
            }
            // stores drain at next chunk's stage barrier (amortized)
        }
    }

    if ((tid & 7) == 0) {
        out[(size_t)BB * SS + (size_t)b * HH + u] = hh;
        out[(size_t)BB * SS + (size_t)BB * HH + (size_t)b * HH + u] = cc;
    }
    if (b == 0 && tid == 0) {
        out[(size_t)BB * SS + 2 * (size_t)BB * HH] = expf(log_thr[0]);
    }
}

// ================= Kernel 2: LN + MLP + head, massively parallel =================
__global__ __launch_bounds__(256, 2)
void post_mlp(const float* __restrict__ hist,
              const float* __restrict__ ln_g,
              const float* __restrict__ ln_b,
              const float* __restrict__ W1,
              const float* __restrict__ b1,
              const float* __restrict__ W2,
              const float* __restrict__ b2,
              const float* __restrict__ Wo,
              const float* __restrict__ bo,
              const float* __restrict__ log_thr,
              float* __restrict__ out) {
    __shared__ float s_rows[256][HH + 1];
    __shared__ __align__(16) float s_W1[HH * HH];
    __shared__ __align__(16) float s_W2[HH * HH];
    __shared__ float s_lng[HH], s_lnb[HH], s_Wo[HH], s_b1[HH], s_b2[HH];

    const int tid = threadIdx.x;
    const size_t base = (size_t)blockIdx.x * 256 * HH;

    for (int i = tid; i < HH * HH; i += 256) { s_W1[i] = W1[i]; s_W2[i] = W2[i]; }
    if (tid < HH) {
        s_lng[tid] = ln_g[tid]; s_lnb[tid] = ln_b[tid]; s_Wo[tid] = Wo[tid];
        s_b1[tid] = b1[tid]; s_b2[tid] = b2[tid];
    }
    for (int i = tid; i < 256 * HH; i += 256)
        s_rows[i / HH][i % HH] = hist[base + i];
    __syncthreads();

    const float bo0 = bo[0];
    const float thrv = expf(log_thr[0]);

    float hv[HH];
#pragma unroll
    for (int k = 0; k < HH; ++k) hv[k] = s_rows[tid][k];
    float m0 = 0.f, m1 = 0.f, q0 = 0.f, q1 = 0.f;
#pragma unroll
    for (int k = 0; k < HH; k += 2) {
        m0 += hv[k]; m1 += hv[k + 1];
        q0 = fmaf(hv[k], hv[k], q0); q1 = fmaf(hv[k + 1], hv[k + 1], q1);
    }
    float mu = (m0 + m1) * (1.0f / HH);
    float var = (q0 + q1) * (1.0f / HH) - mu * mu;
    float inv = 1.0f / sqrtf(var + 1e-5f);
#pragma unroll
    for (int k = 0; k < HH; ++k)
        hv[k] = fmaf((hv[k] - mu) * inv, s_lng[k], s_lnb[k]);

    float part = 0.f;
#pragma unroll
    for (int k = 0; k < HH; ++k)
        part = fmaf(sigm_fast(hv[k]), s_Wo[k], part);

#pragma unroll 2
    for (int j = 0; j < HH; ++j) {
        const float4* wr = (const float4*)&s_W1[j * HH];
        float a0 = s_b1[j], a1 = 0.f;
#pragma unroll
        for (int q = 0; q < 10; ++q) {
            float4 w4 = wr[q];
            a0 = fmaf(w4.x, hv[4*q+0], a0); a1 = fmaf(w4.y, hv[4*q+1], a1);
            a0 = fmaf(w4.z, hv[4*q+2], a0); a1 = fmaf(w4.w, hv[4*q+3], a1);
        }
        s_rows[tid][j] = tanh_fast(a0 + a1);
    }
    float rr[HH];
#pragma unroll
    for (int k = 0; k < HH; ++k) rr[k] = s_rows[tid][k];
#pragma unroll 2
    for (int j = 0; j < HH; ++j) {
        const float4* wr = (const float4*)&s_W2[j * HH];
        float a0 = s_b2[j], a1 = 0.f;
#pragma unroll
        for (int q = 0; q < 10; ++q) {
            float4 w4 = wr[q];
            a0 = fmaf(w4.x, rr[4*q+0], a0); a1 = fmaf(w4.y, rr[4*q+1], a1);
            a0 = fmaf(w4.z, rr[4*q+2], a0); a1 = fmaf(w4.w, rr[4*q+3], a1);
        }
        float r2 = tanh_fast(a0 + a1);
        part = fmaf(r2, s_Wo[j], part);
    }
    float raw = tanh_fast(part + bo0);
    float sg = (fabsf(raw) >= thrv) ? raw : 0.0f;
    out[(size_t)blockIdx.x * 256 + tid] = sg;
}

// ================= Fallback: single fused kernel (ws too small) =================
__global__ __launch_bounds__(256, 2)
void lstm_fused(const float* __restrict__ x, const float* __restrict__ W_ih,
                const float* __restrict__ W_hh, const float* __restrict__ b_ih,
                const float* __restrict__ b_hh, const float* __restrict__ ln_g,
                const float* __restrict__ ln_b, const float* __restrict__ W1,
                const float* __restrict__ b1, const float* __restrict__ W2,
                const float* __restrict__ b2, const float* __restrict__ Wo,
                const float* __restrict__ bo, const float* __restrict__ log_thr,
                float* __restrict__ out) {
    __shared__ float s_ring[CH][RS];
    __shared__ __align__(16) float s_h[2][HS];
    __shared__ __align__(16) float s_x[CH][20];
    __shared__ __align__(16) float s_W1[HH * HH];
    __shared__ __align__(16) float s_W2[HH * HH];
    __shared__ float s_lng[HH], s_lnb[HH], s_Wo[HH], s_b1[HH], s_b2[HH];
    __shared__ float s_part[256];

    const int tid = threadIdx.x;
    const int b = blockIdx.x;
    for (int i = tid; i < HH * HH; i += 256) { s_W1[i] = W1[i]; s_W2[i] = W2[i]; }
    if (tid < HH) {
        s_lng[tid] = ln_g[tid]; s_lnb[tid] = ln_b[tid]; s_Wo[tid] = Wo[tid];
        s_b1[tid] = b1[tid]; s_b2[tid] = b2[tid];
    }
    if (tid < HS) { s_h[0][tid] = 0.0f; s_h[1][tid] = 0.0f; }
    const float bo0 = bo[0];
    const float thrv = expf(log_thr[0]);
    const bool isGate = tid < 4 * HH;
    const int g = tid & 3, u = tid >> 2;
    const int grow = g * HH + u;
    const float mulk = (g == 2) ? 2.0f : 1.0f;
    float wih[DD], whh[HH], bsum = 0.0f;
    if (isGate) {
#pragma unroll
        for (int d = 0; d < DD; ++d) wih[d] = W_ih[grow * DD + d];
        const float4* wr = (const float4*)&W_hh[grow * HH];
#pragma unroll
        for (int q = 0; q < 10; ++q) {
            float4 f = wr[q];
            whh[4*q] = f.x; whh[4*q+1] = f.y; whh[4*q+2] = f.z; whh[4*q+3] = f.w;
        }
        bsum = b_ih[grow] + b_hh[grow];
    }
    float cc = 0.0f, hh = 0.0f;
    const int i0 = tid, i1 = tid + 256, i2 = tid + 512;
    const int st0 = i0 / DD, d0 = i0 % DD;
    const int st1 = i1 / DD, d1 = i1 % DD;
    const int st2 = i2 / DD, d2 = i2 % DD;
    float xr0 = 0.f, xr1 = 0.f, xr2 = 0.f;
    {
        const float* xp = x + (size_t)b * SS * DD;
        xr0 = xp[i0]; xr1 = xp[i1];
        if (i2 < CH * DD) xr2 = xp[i2];
    }
    __syncthreads();
    for (int ch = 0; ch < NCH; ++ch) {
        s_x[st0][d0] = xr0; s_x[st1][d1] = xr1;
        if (i2 < CH * DD) s_x[st2][d2] = xr2;
        if (ch + 1 < NCH) {
            const float* xp = x + ((size_t)b * SS + (size_t)(ch + 1) * CH) * DD;
            xr0 = xp[i0]; xr1 = xp[i1];
            if (i2 < CH * DD) xr2 = xp[i2];
        }
        __syncthreads();
        for (int t = 0; t < CH; ++t) {
            if (isGate) {
                const float4* h4 = (const float4*)s_h[t & 1];
                const float4* x4 = (const float4*)&s_x[t][0];
                float a0 = bsum, a1 = 0.f, a2 = 0.f, a3 = 0.f;
                float4 xa = x4[0], xb = x4[1], xc = x4[2], xd = x4[3], xe = x4[4];
                a0 = fmaf(xa.x, wih[0], a0);  a1 = fmaf(xa.y, wih[1], a1);
                a2 = fmaf(xa.z, wih[2], a2);  a3 = fmaf(xa.w, wih[3], a3);
                a0 = fmaf(xb.x, wih[4], a0);  a1 = fmaf(xb.y, wih[5], a1);
                a2 = fmaf(xb.z, wih[6], a2);  a3 = fmaf(xb.w, wih[7], a3);
                a0 = fmaf(xc.x, wih[8], a0);  a1 = fmaf(xc.y, wih[9], a1);
                a2 = fmaf(xc.z, wih[10], a2); a3 = fmaf(xc.w, wih[11], a3);
                a0 = fmaf(xd.x, wih[12], a0); a1 = fmaf(xd.y, wih[13], a1);
                a2 = fmaf(xd.z, wih[14], a2); a3 = fmaf(xd.w, wih[15], a3);
                a0 = fmaf(xe.x, wih[16], a0); a1 = fmaf(xe.y, wih[17], a1);
                a2 = fmaf(xe.z, wih[18], a2);
#pragma unroll
                for (int q = 0; q < 10; ++q) {
                    float4 f = h4[q];
                    a0 = fmaf(f.x, whh[4*q+0], a0);
                    a1 = fmaf(f.y, whh[4*q+1], a1);
                    a2 = fmaf(f.z, whh[4*q+2], a2);
                    a3 = fmaf(f.w, whh[4*q+3], a3);
                }
                float acc = (a0 + a1) + (a2 + a3);
                float av = gate_act(acc, mulk);
                float bv = __shfl_xor(av, 1);
                float cv = __shfl_xor(av, 2);
                float dv = __shfl_xor(bv, 2);
                if (g == 0) {
                    cc = fmaf(bv, cc, av * cv);
                    hh = dv * tanh_fast(cc);
                    s_h[(t + 1) & 1][u] = hh;
                    s_ring[t][u] = hh;
                }
            }
            __syncthreads();
        }
        {
            const int st = tid & 31;
            const int q8 = tid >> 5;
            float hv[HH];
#pragma unroll
            for (int k = 0; k < HH; ++k) hv[k] = s_ring[st][k];
            float m0 = 0.f, m1 = 0.f, q0 = 0.f, q1 = 0.f;
#pragma unroll
            for (int k = 0; k < HH; k += 2) {
                m0 += hv[k]; m1 += hv[k + 1];
                q0 = fmaf(hv[k], hv[k], q0); q1 = fmaf(hv[k + 1], hv[k + 1], q1);
            }
            float mu = (m0 + m1) * (1.0f / HH);
            float var = (q0 + q1) * (1.0f / HH) - mu * mu;
            float inv = 1.0f / sqrtf(var + 1e-5f);
#pragma unroll
            for (int k = 0; k < HH; ++k)
                hv[k] = fmaf((hv[k] - mu) * inv, s_lng[k], s_lnb[k]);
            float part = 0.f;
#pragma unroll
            for (int k = 0; k < HH; ++k)
                part = fmaf(sigm_fast(hv[k]), s_Wo[k], part);
            if (q8 != 0) part = 0.f;
            __syncthreads();
            float r1v[5];
#pragma unroll
            for (int jj = 0; jj < 5; ++jj) {
                int j = q8 * 5 + jj;
                const float4* wr = (const float4*)&s_W1[j * HH];
                float a0 = s_b1[j], a1 = 0.f;
#pragma unroll
                for (int q = 0; q < 10; ++q) {
                    float4 w4 = wr[q];
                    a0 = fmaf(w4.x, hv[4*q+0], a0); a1 = fmaf(w4.y, hv[4*q+1], a1);
                    a0 = fmaf(w4.z, hv[4*q+2], a0); a1 = fmaf(w4.w, hv[4*q+3], a1);
                }
                r1v[jj] = tanh_fast(a0 + a1);
                s_ring[st][j] = r1v[jj];
            }
            __syncthreads();
            float rr[HH];
#pragma unroll
            for (int k = 0; k < HH; ++k) rr[k] = s_ring[st][k];
#pragma unroll
            for (int jj = 0; jj < 5; ++jj) {
                int j = q8 * 5 + jj;
                const float4* wr = (const float4*)&s_W2[j * HH];
                float a0 = s_b2[j], a1 = 0.f;
#pragma unroll
                for (int q = 0; q < 10; ++q) {
                    float4 w4 = wr[q];
                    a0 = fmaf(w4.x, rr[4*q+0], a0); a1 = fmaf(w4.y, rr[4*q+1], a1);
                    a0 = fmaf(w4.z, rr[4*q+2], a0); a1 = fmaf(w4.w, rr[4*q+3], a1);
                }
                float r2 = tanh_fast(a0 + a1);
                part = fmaf(r2, s_Wo[j], part);
            }
            s_part[tid] = part;
            __syncthreads();
            if (tid < CH) {
                float tot = bo0;
#pragma unroll
                for (int qq = 0; qq < 8; ++qq) tot += s_part[tid + 32 * qq];
                float raw = tanh_fast(tot);
                float sg = (fabsf(raw) >= thrv) ? raw : 0.0f;
                out[(size_t)b * SS + (size_t)ch * CH + tid] = sg;
            }
        }
    }
    if (isGate && g == 0) {
        out[(size_t)BB * SS + (size_t)b * HH + u] = hh;
        out[(size_t)BB * SS + (size_t)BB * HH + (size_t)b * HH + u] = cc;
    }
    if (b == 0 && tid == 0) {
        out[(size_t)BB * SS + 2 * (size_t)BB * HH] = thrv;
    }
}

extern "C" void kernel_launch(void* const* d_in, const int* in_sizes, int n_in,
                              void* d_out, int out_size, void* d_ws, size_t ws_size,
                              hipStream_t stream) {
    const float* x    = (const float*)d_in[0];
    const float* W_ih = (const float*)d_in[1];
    const float* W_hh = (const float*)d_in[2];
    const float* b_ih = (const float*)d_in[3];
    const float* b_hh = (const float*)d_in[4];
    const float* ln_g = (const float*)d_in[5];
    const float* ln_b = (const float*)d_in[6];
    const float* W1   = (const float*)d_in[7];
    const float* b1   = (const float*)d_in[8];
    const float* W2   = (const float*)d_in[9];
    const float* b2   = (const float*)d_in[10];
    const float* Wo   = (const float*)d_in[11];
    const float* bo   = (const float*)d_in[12];
    const float* lt   = (const float*)d_in[13];
    float* out = (float*)d_out;

    const size_t need_hist = (size_t)BB * SS * HH * sizeof(float);   // 168 MB
    if (ws_size >= need_hist) {
        float* hist = (float*)d_ws;
        lstm_seq<<<dim3(BB), dim3(GT), 0, stream>>>(
            x, W_ih, W_hh, b_ih, b_hh, lt, hist, out);
        post_mlp<<<dim3(BB * SS / 256), dim3(256), 0, stream>>>(
            hist, ln_g, ln_b, W1, b1, W2, b2, Wo, bo, lt, out);
    } else {
        lstm_fused<<<dim3(BB), dim3(256), 0, stream>>>(
            x, W_ih, W_hh, b_ih, b_hh, ln_g, ln_b, W1, b1, W2, b2, Wo, bo, lt, out);
    }
}

// Round 20
// 874.920 us; speedup vs baseline: 6.0450x; 1.0162x over previous
//
#include <hip/hip_runtime.h>
#include <math.h>

#define BB 512
#define SS 2048
#define DD 19
#define HH 40
#define CH 32
#define NCH (SS / CH)   // 64 chunks
#define RS 41
#define HS 48
#define GT 320          // gate threads: 5 waves, tid = 8u + 4*half + g

// quad_perm DPP (VALU pipe): xor1=0xB1, xor2=0x4E, rev=0x1B (validated R8/R14)
#define QPERM(v, ctrl) __int_as_float(__builtin_amdgcn_mov_dpp(__float_as_int(v), (ctrl), 0xf, 0xf, true))
// row_half_mirror: lane j -> 7-(j&7) within 8-lane group (validated R15)
#define HMIR(v) __int_as_float(__builtin_amdgcn_mov_dpp(__float_as_int(v), 0x141, 0xf, 0xf, true))

__device__ __forceinline__ float gate_act(float a, float mulk) {
    float e = __expf(a * mulk);
    float r = __builtin_amdgcn_rcpf(e + 1.0f);
    return fmaf(-mulk, r, 1.0f);
}
__device__ __forceinline__ float tanh_fast(float x) {
    float e = __expf(2.0f * x);
    float r = __builtin_amdgcn_rcpf(e + 1.0f);
    return fmaf(-2.0f, r, 1.0f);
}
__device__ __forceinline__ float sigm_fast(float x) {
    float e = __expf(x);
    float r = __builtin_amdgcn_rcpf(e + 1.0f);
    return fmaf(-1.0f, r, 1.0f);
}

// ========== Kernel 1: recurrence; half-major x layout -> 3x b128 xv reads ==========
__global__ __launch_bounds__(GT, 1)
void lstm_seq(const float* __restrict__ x,
              const float* __restrict__ W_ih,
              const float* __restrict__ W_hh,
              const float* __restrict__ b_ih,
              const float* __restrict__ b_hh,
              const float* __restrict__ log_thr,
              float* __restrict__ hist,
              float* __restrict__ out) {
    __shared__ __align__(16) float s_h[2][HS];
    __shared__ __align__(16) float s_x2[2][CH][12];   // [half][t][0..9]=x, 48B rows
    __shared__ float s_hist[CH][HS];                  // per-chunk h history (LDS)

    const int tid = threadIdx.x;
    const int b = blockIdx.x;
    if (tid < HS) { s_h[0][tid] = 0.0f; s_h[1][tid] = 0.0f; }
    if (tid < CH) s_x2[1][tid][9] = 0.0f;   // half1 has 9 data vals; [9] must be 0

    // tid = 8u + 4*half + g : quad holds the 4 gates of one (unit, half)
    const int u = tid >> 3;          // unit 0..39
    const int half = (tid >> 2) & 1; // half of the 40-dim h dot
    const int g = tid & 3;           // gate 0..3
    const int grow = g * HH + u;
    const float mulk = (g == 2) ? 2.0f : 1.0f;

    // ---- weights: HALF a row per thread -> low pressure, VGPR-resident ----
    float whh[20];
    {
        const float4* wr = (const float4*)&W_hh[grow * HH + half * 20];
#pragma unroll
        for (int q = 0; q < 5; ++q) {
            float4 f = wr[q];
            whh[4*q] = f.x; whh[4*q+1] = f.y; whh[4*q+2] = f.z; whh[4*q+3] = f.w;
        }
    }
    float wih[10];
#pragma unroll
    for (int d = 0; d < 10; ++d) {
        int idx = half * 10 + d;
        wih[d] = (idx < DD) ? W_ih[grow * DD + idx] : 0.0f;   // wih[9]=0 for half 1
    }
    const float bsumv = half ? 0.0f : (b_ih[grow] + b_hh[grow]);

    float cc = 0.0f, hh = 0.0f;      // live in (tid&7)==0 lanes

    // x prefetch: 608 floats / 320 threads -> 2 regs; target split by half
    const int i0 = tid, i1 = tid + GT;
    const int st0 = i0 / DD, d0 = i0 % DD;
    const int st1 = i1 / DD, d1 = i1 % DD;
    const int h0_ = (d0 < 10) ? 0 : 1, c0_ = (d0 < 10) ? d0 : d0 - 10;
    const int h1_ = (d1 < 10) ? 0 : 1, c1_ = (d1 < 10) ? d1 : d1 - 10;
    const bool has1 = (i1 < CH * DD);
    float xr0, xr1 = 0.f;
    {
        const float* xp = x + (size_t)b * SS * DD;
        xr0 = xp[i0];
        if (has1) xr1 = xp[i1];
    }

    float* hb = hist + (size_t)b * SS * HH;
    __syncthreads();

    for (int ch = 0; ch < NCH; ++ch) {
        s_x2[h0_][st0][c0_] = xr0;
        if (has1) s_x2[h1_][st1][c1_] = xr1;
        if (ch + 1 < NCH) {
            const float* xp = x + ((size_t)b * SS + (size_t)(ch + 1) * CH) * DD;
            xr0 = xp[i0];
            if (has1) xr1 = xp[i1];
        }
        __syncthreads();   // drains: prefetch loads + prev chunk's hist-copy stores

        // xpart for t=0: 3x b128 (broadcast rows) + 10 FMAs
        float xpart;
        {
            const float4* xs4 = (const float4*)&s_x2[half][0][0];
            float4 X0 = xs4[0], X1 = xs4[1], X2 = xs4[2];
            float p0 = bsumv, p1 = 0.f;
            p0 = fmaf(X0.x, wih[0], p0); p1 = fmaf(X0.y, wih[1], p1);
            p0 = fmaf(X0.z, wih[2], p0); p1 = fmaf(X0.w, wih[3], p1);
            p0 = fmaf(X1.x, wih[4], p0); p1 = fmaf(X1.y, wih[5], p1);
            p0 = fmaf(X1.z, wih[6], p0); p1 = fmaf(X1.w, wih[7], p1);
            p0 = fmaf(X2.x, wih[8], p0); p1 = fmaf(X2.y, wih[9], p1);
            xpart = p0 + p1;
        }

        for (int t = 0; t < CH; ++t) {
            // hoist t+1 x reads BEFORE h reads (3 b128; latency overlaps h-dot)
            float4 X0, X1, X2;
            if (t + 1 < CH) {
                const float4* xs4 = (const float4*)&s_x2[half][t + 1][0];
                X0 = xs4[0]; X1 = xs4[1]; X2 = xs4[2];
            }
            // ---- critical region: 5 x b128 h-reads + 20 FMAs ----
            const float4* h4 = (const float4*)&s_h[t & 1][half * 20];
            float a0 = xpart, a1 = 0.f;
#pragma unroll
            for (int q = 0; q < 5; ++q) {
                float4 f = h4[q];
                a0 = fmaf(f.x, whh[4*q+0], a0);
                a1 = fmaf(f.y, whh[4*q+1], a1);
                a0 = fmaf(f.z, whh[4*q+2], a0);
                a1 = fmaf(f.w, whh[4*q+3], a1);
            }
            float acc = a0 + a1;
            // half-combine entirely on VALU: half_mirror then quad-reverse
            float other = QPERM(HMIR(acc), 0x1B);
            float full = acc + other;
            float av = gate_act(full, mulk);
            // gate exchange: quad-internal DPP, all direct from av
            float bv = QPERM(av, 0xB1);   // gate g^1
            float cv = QPERM(av, 0x4E);   // gate g^2
            float dv = QPERM(av, 0x1B);   // gate g^3
            // lane 8u+0: av=i, bv=f, cv=g~, dv=o
            if ((tid & 7) == 0) {
                cc = fmaf(bv, cc, av * cv);
                hh = dv * tanh_fast(cc);
                s_h[(t + 1) & 1][u] = hh;
                s_hist[t][u] = hh;        // LDS, not global: no vmcnt at barrier
            }
            if (t + 1 < CH) {   // xpart for t+1 from already-loaded regs (off-chain)
                float p0 = bsumv, p1 = 0.f;
                p0 = fmaf(X0.x, wih[0], p0); p1 = fmaf(X0.y, wih[1], p1);
                p0 = fmaf(X0.z, wih[2], p0); p1 = fmaf(X0.w, wih[3], p1);
                p0 = fmaf(X1.x, wih[4], p0); p1 = fmaf(X1.y, wih[5], p1);
                p0 = fmaf(X1.z, wih[6], p0); p1 = fmaf(X1.w, wih[7], p1);
                p0 = fmaf(X2.x, wih[8], p0); p1 = fmaf(X2.y, wih[9], p1);
                xpart = p0 + p1;
            }
            __syncthreads();
        }

        // ---- chunk-end: cooperative coalesced copy s_hist -> global hist ----
        {
            const size_t cb = (size_t)ch * CH * HH;
#pragma unroll
            for (int it = 0; it < 4; ++it) {
                int i = tid + it * GT;                // CH*HH = 1280 = 4*GT
                hb[cb + i] = s_hist[i / HH][i % HH];
            }
        }
    }

    if ((tid & 7) == 0) {
        out[(size_t)BB * SS + (size_t)b * HH + u] = hh;
        out[(size_t)BB * SS + (size_t)BB * HH + (size_t)b * HH + u] = cc;
    }
    if (b == 0 && tid == 0) {
        out[(size_t)BB * SS + 2 * (size_t)BB * HH] = expf(log_thr[0]);
    }
}

// ================= Kernel 2: LN + MLP + head, massively parallel =================
__global__ __launch_bounds__(256, 2)
void post_mlp(const float* __restrict__ hist,
              const float* __restrict__ ln_g,
              const float* __restrict__ ln_b,
              const float* __restrict__ W1,
              const float* __restrict__ b1,
              const float* __restrict__ W2,
              const float* __restrict__ b2,
              const float* __restrict__ Wo,
              const float* __restrict__ bo,
              const float* __restrict__ log_thr,
              float* __restrict__ out) {
    __shared__ float s_rows[256][HH + 1];
    __shared__ __align__(16) float s_W1[HH * HH];
    __shared__ __align__(16) float s_W2[HH * HH];
    __shared__ float s_lng[HH], s_lnb[HH], s_Wo[HH], s_b1[HH], s_b2[HH];

    const int tid = threadIdx.x;
    const size_t base = (size_t)blockIdx.x * 256 * HH;

    for (int i = tid; i < HH * HH; i += 256) { s_W1[i] = W1[i]; s_W2[i] = W2[i]; }
    if (tid < HH) {
        s_lng[tid] = ln_g[tid]; s_lnb[tid] = ln_b[tid]; s_Wo[tid] = Wo[tid];
        s_b1[tid] = b1[tid]; s_b2[tid] = b2[tid];
    }
    for (int i = tid; i < 256 * HH; i += 256)
        s_rows[i / HH][i % HH] = hist[base + i];
    __syncthreads();

    const float bo0 = bo[0];
    const float thrv = expf(log_thr[0]);

    float hv[HH];
#pragma unroll
    for (int k = 0; k < HH; ++k) hv[k] = s_rows[tid][k];
    float m0 = 0.f, m1 = 0.f, q0 = 0.f, q1 = 0.f;
#pragma unroll
    for (int k = 0; k < HH; k += 2) {
        m0 += hv[k]; m1 += hv[k + 1];
        q0 = fmaf(hv[k], hv[k], q0); q1 = fmaf(hv[k + 1], hv[k + 1], q1);
    }
    float mu = (m0 + m1) * (1.0f / HH);
    float var = (q0 + q1) * (1.0f / HH) - mu * mu;
    float inv = 1.0f / sqrtf(var + 1e-5f);
#pragma unroll
    for (int k = 0; k < HH; ++k)
        hv[k] = fmaf((hv[k] - mu) * inv, s_lng[k], s_lnb[k]);

    float part = 0.f;
#pragma unroll
    for (int k = 0; k < HH; ++k)
        part = fmaf(sigm_fast(hv[k]), s_Wo[k], part);

#pragma unroll 2
    for (int j = 0; j < HH; ++j) {
        const float4* wr = (const float4*)&s_W1[j * HH];
        float a0 = s_b1[j], a1 = 0.f;
#pragma unroll
        for (int q = 0; q < 10; ++q) {
            float4 w4 = wr[q];
            a0 = fmaf(w4.x, hv[4*q+0], a0); a1 = fmaf(w4.y, hv[4*q+1], a1);
            a0 = fmaf(w4.z, hv[4*q+2], a0); a1 = fmaf(w4.w, hv[4*q+3], a1);
        }
        s_rows[tid][j] = tanh_fast(a0 + a1);
    }
    float rr[HH];
#pragma unroll
    for (int k = 0; k < HH; ++k) rr[k] = s_rows[tid][k];
#pragma unroll 2
    for (int j = 0; j < HH; ++j) {
        const float4* wr = (const float4*)&s_W2[j * HH];
        float a0 = s_b2[j], a1 = 0.f;
#pragma unroll
        for (int q = 0; q < 10; ++q) {
            float4 w4 = wr[q];
            a0 = fmaf(w4.x, rr[4*q+0], a0); a1 = fmaf(w4.y, rr[4*q+1], a1);
            a0 = fmaf(w4.z, rr[4*q+2], a0); a1 = fmaf(w4.w, rr[4*q+3], a1);
        }
        float r2 = tanh_fast(a0 + a1);
        part = fmaf(r2, s_Wo[j], part);
    }
    float raw = tanh_fast(part + bo0);
    float sg = (fabsf(raw) >= thrv) ? raw : 0.0f;
    out[(size_t)blockIdx.x * 256 + tid] = sg;
}

// ================= Fallback: single fused kernel (ws too small) =================
__global__ __launch_bounds__(256, 2)
void lstm_fused(const float* __restrict__ x, const float* __restrict__ W_ih,
                const float* __restrict__ W_hh, const float* __restrict__ b_ih,
                const float* __restrict__ b_hh, const float* __restrict__ ln_g,
                const float* __restrict__ ln_b, const float* __restrict__ W1,
                const float* __restrict__ b1, const float* __restrict__ W2,
                const float* __restrict__ b2, const float* __restrict__ Wo,
                const float* __restrict__ bo, const float* __restrict__ log_thr,
                float* __restrict__ out) {
    __shared__ float s_ring[CH][RS];
    __shared__ __align__(16) float s_h[2][HS];
    __shared__ __align__(16) float s_x[CH][20];
    __shared__ __align__(16) float s_W1[HH * HH];
    __shared__ __align__(16) float s_W2[HH * HH];
    __shared__ float s_lng[HH], s_lnb[HH], s_Wo[HH], s_b1[HH], s_b2[HH];
    __shared__ float s_part[256];

    const int tid = threadIdx.x;
    const int b = blockIdx.x;
    for (int i = tid; i < HH * HH; i += 256) { s_W1[i] = W1[i]; s_W2[i] = W2[i]; }
    if (tid < HH) {
        s_lng[tid] = ln_g[tid]; s_lnb[tid] = ln_b[tid]; s_Wo[tid] = Wo[tid];
        s_b1[tid] = b1[tid]; s_b2[tid] = b2[tid];
    }
    if (tid < HS) { s_h[0][tid] = 0.0f; s_h[1][tid] = 0.0f; }
    const float bo0 = bo[0];
    const float thrv = expf(log_thr[0]);
    const bool isGate = tid < 4 * HH;
    const int g = tid & 3, u = tid >> 2;
    const int grow = g * HH + u;
    const float mulk = (g == 2) ? 2.0f : 1.0f;
    float wih[DD], whh[HH], bsum = 0.0f;
    if (isGate) {
#pragma unroll
        for (int d = 0; d < DD; ++d) wih[d] = W_ih[grow * DD + d];
        const float4* wr = (const float4*)&W_hh[grow * HH];
#pragma unroll
        for (int q = 0; q < 10; ++q) {
            float4 f = wr[q];
            whh[4*q] = f.x; whh[4*q+1] = f.y; whh[4*q+2] = f.z; whh[4*q+3] = f.w;
        }
        bsum = b_ih[grow] + b_hh[grow];
    }
    float cc = 0.0f, hh = 0.0f;
    const int i0 = tid, i1 = tid + 256, i2 = tid + 512;
    const int st0 = i0 / DD, d0 = i0 % DD;
    const int st1 = i1 / DD, d1 = i1 % DD;
    const int st2 = i2 / DD, d2 = i2 % DD;
    float xr0 = 0.f, xr1 = 0.f, xr2 = 0.f;
    {
        const float* xp = x + (size_t)b * SS * DD;
        xr0 = xp[i0]; xr1 = xp[i1];
        if (i2 < CH * DD) xr2 = xp[i2];
    }
    __syncthreads();
    for (int ch = 0; ch < NCH; ++ch) {
        s_x[st0][d0] = xr0; s_x[st1][d1] = xr1;
        if (i2 < CH * DD) s_x[st2][d2] = xr2;
        if (ch + 1 < NCH) {
            const float* xp = x + ((size_t)b * SS + (size_t)(ch + 1) * CH) * DD;
            xr0 = xp[i0]; xr1 = xp[i1];
            if (i2 < CH * DD) xr2 = xp[i2];
        }
        __syncthreads();
        for (int t = 0; t < CH; ++t) {
            if (isGate) {
                const float4* h4 = (const float4*)s_h[t & 1];
                const float4* x4 = (const float4*)&s_x[t][0];
                float a0 = bsum, a1 = 0.f, a2 = 0.f, a3 = 0.f;
                float4 xa = x4[0], xb = x4[1], xc = x4[2], xd = x4[3], xe = x4[4];
                a0 = fmaf(xa.x, wih[0], a0);  a1 = fmaf(xa.y, wih[1], a1);
                a2 = fmaf(xa.z, wih[2], a2);  a3 = fmaf(xa.w, wih[3], a3);
                a0 = fmaf(xb.x, wih[4], a0);  a1 = fmaf(xb.y, wih[5], a1);
                a2 = fmaf(xb.z, wih[6], a2);  a3 = fmaf(xb.w, wih[7], a3);
                a0 = fmaf(xc.x, wih[8], a0);  a1 = fmaf(xc.y, wih[9], a1);
                a2 = fmaf(xc.z, wih[10], a2); a3 = fmaf(xc.w, wih[11], a3);
                a0 = fmaf(xd.x, wih[12], a0); a1 = fmaf(xd.y, wih[13], a1);
                a2 = fmaf(xd.z, wih[14], a2); a3 = fmaf(xd.w, wih[15], a3);
                a0 = fmaf(xe.x, wih[16], a0); a1 = fmaf(xe.y, wih[17], a1);
                a2 = fmaf(xe.z, wih[18], a2);
#pragma unroll
                for (int q = 0; q < 10; ++q) {
                    float4 f = h4[q];
                    a0 = fmaf(f.x, whh[4*q+0], a0);
                    a1 = fmaf(f.y, whh[4*q+1], a1);
                    a2 = fmaf(f.z, whh[4*q+2], a2);
                    a3 = fmaf(f.w, whh[4*q+3], a3);
                }
                float acc = (a0 + a1) + (a2 + a3);
                float av = gate_act(acc, mulk);
                float bv = __shfl_xor(av, 1);
                float cv = __shfl_xor(av, 2);
                float dv = __shfl_xor(bv, 2);
                if (g == 0) {
                    cc = fmaf(bv, cc, av * cv);
                    hh = dv * tanh_fast(cc);
                    s_h[(t + 1) & 1][u] = hh;
                    s_ring[t][u] = hh;
                }
            }
            __syncthreads();
        }
        {
            const int st = tid & 31;
            const int q8 = tid >> 5;
            float hv[HH];
#pragma unroll
            for (int k = 0; k < HH; ++k) hv[k] = s_ring[st][k];
            float m0 = 0.f, m1 = 0.f, q0 = 0.f, q1 = 0.f;
#pragma unroll
            for (int k = 0; k < HH; k += 2) {
                m0 += hv[k]; m1 += hv[k + 1];
                q0 = fmaf(hv[k], hv[k], q0); q1 = fmaf(hv[k + 1], hv[k + 1], q1);
            }
            float mu = (m0 + m1) * (1.0f / HH);
            float var = (q0 + q1) * (1.0f / HH) - mu * mu;
            float inv = 1.0f / sqrtf(var + 1e-5f);
#pragma unroll
            for (int k = 0; k < HH; ++k)
                hv[k] = fmaf((hv[k] - mu) * inv, s_lng[k], s_lnb[k]);
            float part = 0.f;
#pragma unroll
            for (int k = 0; k < HH; ++k)
                part = fmaf(sigm_fast(hv[k]), s_Wo[k], part);
            if (q8 != 0) part = 0.f;
            __syncthreads();
            float r1v[5];
#pragma unroll
            for (int jj = 0; jj < 5; ++jj) {
                int j = q8 * 5 + jj;
                const float4* wr = (const float4*)&s_W1[j * HH];
                float a0 = s_b1[j], a1 = 0.f;
#pragma unroll
                for (int q = 0; q < 10; ++q) {
                    float4 w4 = wr[q];
                    a0 = fmaf(w4.x, hv[4*q+0], a0); a1 = fmaf(w4.y, hv[4*q+1], a1);
                    a0 = fmaf(w4.z, hv[4*q+2], a0); a1 = fmaf(w4.w, hv[4*q+3], a1);
                }
                r1v[jj] = tanh_fast(a0 + a1);
                s_ring[st][j] = r1v[jj];
            }
            __syncthreads();
            float rr[HH];
#pragma unroll
            for (int k = 0; k < HH; ++k) rr[k] = s_ring[st][k];
#pragma unroll
            for (int jj = 0; jj < 5; ++jj) {
                int j = q8 * 5 + jj;
                const float4* wr = (const float4*)&s_W2[j * HH];
                float a0 = s_b2[j], a1 = 0.f;
#pragma unroll
                for (int q = 0; q < 10; ++q) {
                    float4 w4 = wr[q];
                    a0 = fmaf(w4.x, rr[4*q+0], a0); a1 = fmaf(w4.y, rr[4*q+1], a1);
                    a0 = fmaf(w4.z, rr[4*q+2], a0); a1 = fmaf(w4.w, rr[4*q+3], a1);
                }
                float r2 = tanh_fast(a0 + a1);
                part = fmaf(r2, s_Wo[j], part);
            }
            s_part[tid] = part;
            __syncthreads();
            if (tid < CH) {
                float tot = bo0;
#pragma unroll
                for (int qq = 0; qq < 8; ++qq) tot += s_part[tid + 32 * qq];
                float raw = tanh_fast(tot);
                float sg = (fabsf(raw) >= thrv) ? raw : 0.0f;
                out[(size_t)b * SS + (size_t)ch * CH + tid] = sg;
            }
        }
    }
    if (isGate && g == 0) {
        out[(size_t)BB * SS + (size_t)b * HH + u] = hh;
        out[(size_t)BB * SS + (size_t)BB * HH + (size_t)b * HH + u] = cc;
    }
    if (b == 0 && tid == 0) {
        out[(size_t)BB * SS + 2 * (size_t)BB * HH] = thrv;
    }
}

extern "C" void kernel_launch(void* const* d_in, const int* in_sizes, int n_in,
                              void* d_out, int out_size, void* d_ws, size_t ws_size,
                              hipStream_t stream) {
    const float* x    = (const float*)d_in[0];
    const float* W_ih = (const float*)d_in[1];
    const float* W_hh = (const float*)d_in[2];
    const float* b_ih = (const float*)d_in[3];
    const float* b_hh = (const float*)d_in[4];
    const float* ln_g = (const float*)d_in[5];
    const float* ln_b = (const float*)d_in[6];
    const float* W1   = (const float*)d_in[7];
    const float* b1   = (const float*)d_in[8];
    const float* W2   = (const float*)d_in[9];
    const float* b2   = (const float*)d_in[10];
    const float* Wo   = (const float*)d_in[11];
    const float* bo   = (const float*)d_in[12];
    const float* lt   = (const float*)d_in[13];
    float* out = (float*)d_out;

    const size_t need_hist = (size_t)BB * SS * HH * sizeof(float);   // 168 MB
    if (ws_size >= need_hist) {
        float* hist = (float*)d_ws;
        lstm_seq<<<dim3(BB), dim3(GT), 0, stream>>>(
            x, W_ih, W_hh, b_ih, b_hh, lt, hist, out);
        post_mlp<<<dim3(BB * SS / 256), dim3(256), 0, stream>>>(
            hist, ln_g, ln_b, W1, b1, W2, b2, Wo, bo, lt, out);
    } else {
        lstm_fused<<<dim3(BB), dim3(256), 0, stream>>>(
            x, W_ih, W_hh, b_ih, b_hh, ln_g, ln_b, W1, b1, W2, b2, Wo, bo, lt, out);
    }
}